// Round 1
// baseline (514.943 us; speedup 1.0000x reference)
//
#include <hip/hip_runtime.h>

#define NNODES 50000
#define NEDGES 800000
#define DIM 64

// ---------------------------------------------------------------------------
// deg[row[e]] += ew[e]
__global__ __launch_bounds__(256) void deg_kernel(const int* __restrict__ row,
                                                  const float* __restrict__ ew,
                                                  float* __restrict__ deg, int E) {
    int e = blockIdx.x * 256 + threadIdx.x;
    if (e < E) atomicAdd(&deg[row[e]], ew[e]);
}

// deg -> deg>0 ? rsqrt(deg) : 0   (in place)
__global__ __launch_bounds__(256) void dis_kernel(float* __restrict__ deg, int N) {
    int i = blockIdx.x * 256 + threadIdx.x;
    if (i < N) {
        float d = deg[i];
        deg[i] = d > 0.0f ? rsqrtf(d) : 0.0f;
    }
}

// norm[e] = dis[row[e]] * ew[e] * dis[col[e]]
__global__ __launch_bounds__(256) void norm_kernel(const int* __restrict__ ei,
                                                   const float* __restrict__ ew,
                                                   const float* __restrict__ dis,
                                                   float* __restrict__ norm, int E) {
    int e = blockIdx.x * 256 + threadIdx.x;
    if (e < E) {
        int r = ei[e];
        int c = ei[NEDGES + e];
        norm[e] = dis[r] * ew[e] * dis[c];
    }
}

// H[N,64] = (RELU ? max(X,0) : X) @ W[64,64] + b[64]
// 16 rows per block, 256 threads; thread computes 4 contiguous output cols.
template <bool RELU>
__global__ __launch_bounds__(256) void gemm64_kernel(const float* __restrict__ X,
                                                     const float* __restrict__ W,
                                                     const float* __restrict__ b,
                                                     float* __restrict__ H, int N) {
    __shared__ float Ws[64 * 64];
    __shared__ float Xs[16][65];  // +1 pad: kills 4-way bank conflict on Xs[r][k]

    const int tid = threadIdx.x;
    const int rowBase = blockIdx.x * 16;

    // stage W: 4096 floats = 1024 float4, 4 per thread
    {
        const float4* Wv = (const float4*)W;
        float4* Wsv = (float4*)Ws;
#pragma unroll
        for (int i = 0; i < 4; i++) Wsv[tid + 256 * i] = Wv[tid + 256 * i];
    }
    // stage 16 rows of X: 1024 floats = 256 float4, 1 per thread
    {
        int r = tid >> 4;        // 0..15
        int c4 = tid & 15;       // float4 index within row
        int gr = rowBase + r;
        float4 v = make_float4(0.f, 0.f, 0.f, 0.f);
        if (gr < N) v = ((const float4*)X)[gr * 16 + c4];
        if (RELU) {
            v.x = fmaxf(v.x, 0.f); v.y = fmaxf(v.y, 0.f);
            v.z = fmaxf(v.z, 0.f); v.w = fmaxf(v.w, 0.f);
        }
        Xs[r][c4 * 4 + 0] = v.x;
        Xs[r][c4 * 4 + 1] = v.y;
        Xs[r][c4 * 4 + 2] = v.z;
        Xs[r][c4 * 4 + 3] = v.w;
    }
    __syncthreads();

    const int r = tid >> 4;         // 0..15
    const int c0 = (tid & 15) * 4;  // 0,4,...,60
    float a0 = b[c0 + 0], a1 = b[c0 + 1], a2 = b[c0 + 2], a3 = b[c0 + 3];
#pragma unroll
    for (int k = 0; k < 64; k++) {
        float xv = Xs[r][k];
        float4 wv = *(const float4*)&Ws[k * 64 + c0];
        a0 = fmaf(xv, wv.x, a0);
        a1 = fmaf(xv, wv.y, a1);
        a2 = fmaf(xv, wv.z, a2);
        a3 = fmaf(xv, wv.w, a3);
    }
    int gr = rowBase + r;
    if (gr < N) {
        float4 o = make_float4(a0, a1, a2, a3);
        *(float4*)&H[gr * 64 + c0] = o;
    }
}

// Out[col[e], :] += norm[e] * H[row[e], :]   — one wave per edge, lane = feature
__global__ __launch_bounds__(256) void scatter_kernel(const int* __restrict__ ei,
                                                      const float* __restrict__ norm,
                                                      const float* __restrict__ H,
                                                      float* __restrict__ Out, int E) {
    int wid = blockIdx.x * 4 + (threadIdx.x >> 6);  // edge id
    int lane = threadIdx.x & 63;
    if (wid >= E) return;
    int r = ei[wid];
    int c = ei[NEDGES + wid];
    float nv = norm[wid];
    float v = nv * H[r * DIM + lane];
    atomicAdd(&Out[c * DIM + lane], v);
}

extern "C" void kernel_launch(void* const* d_in, const int* in_sizes, int n_in,
                              void* d_out, int out_size, void* d_ws, size_t ws_size,
                              hipStream_t stream) {
    const float* x  = (const float*)d_in[0];
    const int*   ei = (const int*)d_in[1];   // [2, E] int32
    const float* ew = (const float*)d_in[2];
    const float* W1 = (const float*)d_in[3];
    const float* b1 = (const float*)d_in[4];
    const float* W2 = (const float*)d_in[5];
    const float* b2 = (const float*)d_in[6];
    float* out = (float*)d_out;

    char* ws = (char*)d_ws;
    // layout (bytes): deg/dis [0,200000) | norm [200000,3400000) | h [3400192,...) | agg1
    float* deg  = (float*)(ws);
    float* norm = (float*)(ws + 200000);
    float* h    = (float*)(ws + 3400192);               // reused for h1 and h2
    float* agg1 = (float*)(ws + 3400192 + (size_t)NNODES * DIM * 4);

    const int N = NNODES, E = NEDGES;

    hipMemsetAsync(deg, 0, (size_t)N * 4, stream);
    hipMemsetAsync(agg1, 0, (size_t)N * DIM * 4, stream);
    hipMemsetAsync(out, 0, (size_t)N * DIM * 4, stream);

    deg_kernel<<<(E + 255) / 256, 256, 0, stream>>>(ei, ew, deg, E);
    dis_kernel<<<(N + 255) / 256, 256, 0, stream>>>(deg, N);
    norm_kernel<<<(E + 255) / 256, 256, 0, stream>>>(ei, ew, deg, norm, E);

    // layer 1
    gemm64_kernel<false><<<(N + 15) / 16, 256, 0, stream>>>(x, W1, b1, h, N);
    scatter_kernel<<<(E + 3) / 4, 256, 0, stream>>>(ei, norm, h, agg1, E);

    // layer 2 (ReLU fused into GEMM input load)
    gemm64_kernel<true><<<(N + 15) / 16, 256, 0, stream>>>(agg1, W2, b2, h, N);
    scatter_kernel<<<(E + 3) / 4, 256, 0, stream>>>(ei, norm, h, out, E);
}

// Round 2
// 339.988 us; speedup vs baseline: 1.5146x; 1.5146x over previous
//
#include <hip/hip_runtime.h>

#define NNODES 50000
#define NEDGES 800000
#define DIM 64

// ---------------------------------------------------------------------------
// deg[row[e]] += ew[e]; count[col[e]] += 1     (degree + CSR histogram fused)
__global__ __launch_bounds__(256) void deg_hist_kernel(const int* __restrict__ ei,
                                                       const float* __restrict__ ew,
                                                       float* __restrict__ deg,
                                                       int* __restrict__ count, int E) {
    int e = blockIdx.x * 256 + threadIdx.x;
    if (e < E) {
        atomicAdd(&deg[ei[e]], ew[e]);
        atomicAdd(&count[ei[NEDGES + e]], 1);
    }
}

// deg -> deg>0 ? rsqrt(deg) : 0   (in place)
__global__ __launch_bounds__(256) void dis_kernel(float* __restrict__ deg, int N) {
    int i = blockIdx.x * 256 + threadIdx.x;
    if (i < N) {
        float d = deg[i];
        deg[i] = d > 0.0f ? rsqrtf(d) : 0.0f;
    }
}

// --- 3-phase exclusive scan of count[N] -> rowptr[N] (+ rowptr[N]=E set in p3)
__global__ __launch_bounds__(256) void scan1_kernel(const int* __restrict__ count,
                                                    int* __restrict__ rowptr,
                                                    int* __restrict__ bsum, int N) {
    __shared__ int tmp[256];
    int t = threadIdx.x;
    int i = blockIdx.x * 256 + t;
    int v = (i < N) ? count[i] : 0;
    tmp[t] = v;
    __syncthreads();
#pragma unroll
    for (int off = 1; off < 256; off <<= 1) {
        int add = (t >= off) ? tmp[t - off] : 0;
        __syncthreads();
        tmp[t] += add;
        __syncthreads();
    }
    if (i < N) rowptr[i] = tmp[t] - v;           // exclusive within block
    if (t == 255) bsum[blockIdx.x] = tmp[255];   // block total
}

__global__ __launch_bounds__(256) void scan2_kernel(int* __restrict__ bsum, int B) {
    __shared__ int tmp[256];
    int t = threadIdx.x;
    int v = (t < B) ? bsum[t] : 0;
    tmp[t] = v;
    __syncthreads();
#pragma unroll
    for (int off = 1; off < 256; off <<= 1) {
        int add = (t >= off) ? tmp[t - off] : 0;
        __syncthreads();
        tmp[t] += add;
        __syncthreads();
    }
    if (t < B) bsum[t] = tmp[t] - v;             // exclusive block offsets
}

__global__ __launch_bounds__(256) void scan3_kernel(int* __restrict__ rowptr,
                                                    const int* __restrict__ bsum, int N, int E) {
    int i = blockIdx.x * 256 + threadIdx.x;
    if (i < N) rowptr[i] += bsum[blockIdx.x];
    if (i == 0) rowptr[N] = E;
}

// place edge e at cursor[col]++ ; record (row, norm) packed. norm fused here.
__global__ __launch_bounds__(256) void fill_kernel(const int* __restrict__ ei,
                                                   const float* __restrict__ ew,
                                                   const float* __restrict__ dis,
                                                   int* __restrict__ cursor,
                                                   int2* __restrict__ edata, int E) {
    int e = blockIdx.x * 256 + threadIdx.x;
    if (e < E) {
        int r = ei[e];
        int c = ei[NEDGES + e];
        float nv = dis[r] * ew[e] * dis[c];
        int pos = atomicAdd(&cursor[c], 1);      // cursor pre-initialized to rowptr
        edata[pos] = make_int2(r, __float_as_int(nv));
    }
}

// ---------------------------------------------------------------------------
// H[N,64] = (RELU ? max(X,0) : X) @ W[64,64] + b[64]
template <bool RELU>
__global__ __launch_bounds__(256) void gemm64_kernel(const float* __restrict__ X,
                                                     const float* __restrict__ W,
                                                     const float* __restrict__ b,
                                                     float* __restrict__ H, int N) {
    __shared__ float Ws[64 * 64];
    __shared__ float Xs[16][65];

    const int tid = threadIdx.x;
    const int rowBase = blockIdx.x * 16;

    {
        const float4* Wv = (const float4*)W;
        float4* Wsv = (float4*)Ws;
#pragma unroll
        for (int i = 0; i < 4; i++) Wsv[tid + 256 * i] = Wv[tid + 256 * i];
    }
    {
        int r = tid >> 4;
        int c4 = tid & 15;
        int gr = rowBase + r;
        float4 v = make_float4(0.f, 0.f, 0.f, 0.f);
        if (gr < N) v = ((const float4*)X)[gr * 16 + c4];
        if (RELU) {
            v.x = fmaxf(v.x, 0.f); v.y = fmaxf(v.y, 0.f);
            v.z = fmaxf(v.z, 0.f); v.w = fmaxf(v.w, 0.f);
        }
        Xs[r][c4 * 4 + 0] = v.x;
        Xs[r][c4 * 4 + 1] = v.y;
        Xs[r][c4 * 4 + 2] = v.z;
        Xs[r][c4 * 4 + 3] = v.w;
    }
    __syncthreads();

    const int r = tid >> 4;
    const int c0 = (tid & 15) * 4;
    float a0 = b[c0 + 0], a1 = b[c0 + 1], a2 = b[c0 + 2], a3 = b[c0 + 3];
#pragma unroll
    for (int k = 0; k < 64; k++) {
        float xv = Xs[r][k];
        float4 wv = *(const float4*)&Ws[k * 64 + c0];
        a0 = fmaf(xv, wv.x, a0);
        a1 = fmaf(xv, wv.y, a1);
        a2 = fmaf(xv, wv.z, a2);
        a3 = fmaf(xv, wv.w, a3);
    }
    int gr = rowBase + r;
    if (gr < N) {
        float4 o = make_float4(a0, a1, a2, a3);
        *(float4*)&H[gr * 64 + c0] = o;
    }
}

// ---------------------------------------------------------------------------
// Out[n,:] = sum over incoming edges e of node n: norm[e] * H[row[e],:]
// One wave per node, lane = feature. Edge metadata loaded coalesced 64-wide,
// broadcast per edge via shfl. No atomics; Out written exactly once per node.
__global__ __launch_bounds__(256) void gather_kernel(const int* __restrict__ rowptr,
                                                     const int2* __restrict__ edata,
                                                     const float* __restrict__ H,
                                                     float* __restrict__ Out, int N) {
    int node = blockIdx.x * 4 + (threadIdx.x >> 6);
    int lane = threadIdx.x & 63;
    if (node >= N) return;
    int s = rowptr[node];
    int epos_end = rowptr[node + 1];
    float acc = 0.0f;
    for (int base = s; base < epos_end; base += 64) {
        int m = epos_end - base;
        if (m > 64) m = 64;
        int2 d = make_int2(0, 0);
        if (base + lane < epos_end) d = edata[base + lane];
        for (int j = 0; j < m; j++) {
            int r = __shfl(d.x, j);
            float nv = __int_as_float(__shfl(d.y, j));
            acc = fmaf(nv, H[r * DIM + lane], acc);
        }
    }
    Out[node * DIM + lane] = acc;
}

// ---------------------------------------------------------------------------
extern "C" void kernel_launch(void* const* d_in, const int* in_sizes, int n_in,
                              void* d_out, int out_size, void* d_ws, size_t ws_size,
                              hipStream_t stream) {
    const float* x  = (const float*)d_in[0];
    const int*   ei = (const int*)d_in[1];   // [2, E] int32
    const float* ew = (const float*)d_in[2];
    const float* W1 = (const float*)d_in[3];
    const float* b1 = (const float*)d_in[4];
    const float* W2 = (const float*)d_in[5];
    const float* b2 = (const float*)d_in[6];
    float* out = (float*)d_out;

    const int N = NNODES, E = NEDGES;
    const int SCAN_B = (N + 255) / 256;  // 196

    char* ws = (char*)d_ws;
    size_t off = 0;
    auto alloc = [&](size_t bytes) { char* p = ws + off; off += (bytes + 255) & ~size_t(255); return p; };
    float* deg    = (float*)alloc((size_t)N * 4);        // becomes dis in place
    int*   count  = (int*)  alloc((size_t)N * 4);
    int*   rowptr = (int*)  alloc((size_t)(N + 1) * 4);
    int*   bsum   = (int*)  alloc((size_t)SCAN_B * 4);
    int*   cursor = (int*)  alloc((size_t)N * 4);
    int2*  edata  = (int2*) alloc((size_t)E * 8);
    float* h      = (float*)alloc((size_t)N * DIM * 4);  // reused h1/h2
    float* agg1   = (float*)alloc((size_t)N * DIM * 4);

    hipMemsetAsync(deg, 0, (size_t)N * 4, stream);
    hipMemsetAsync(count, 0, (size_t)N * 4, stream);

    deg_hist_kernel<<<(E + 255) / 256, 256, 0, stream>>>(ei, ew, deg, count, E);
    dis_kernel<<<(N + 255) / 256, 256, 0, stream>>>(deg, N);

    scan1_kernel<<<SCAN_B, 256, 0, stream>>>(count, rowptr, bsum, N);
    scan2_kernel<<<1, 256, 0, stream>>>(bsum, SCAN_B);
    scan3_kernel<<<SCAN_B, 256, 0, stream>>>(rowptr, bsum, N, E);

    hipMemcpyAsync(cursor, rowptr, (size_t)N * 4, hipMemcpyDeviceToDevice, stream);
    fill_kernel<<<(E + 255) / 256, 256, 0, stream>>>(ei, ew, deg, cursor, edata, E);

    // layer 1
    gemm64_kernel<false><<<(N + 15) / 16, 256, 0, stream>>>(x, W1, b1, h, N);
    gather_kernel<<<(N + 3) / 4, 256, 0, stream>>>(rowptr, edata, h, agg1, N);

    // layer 2 (ReLU fused into GEMM input load)
    gemm64_kernel<true><<<(N + 15) / 16, 256, 0, stream>>>(agg1, W2, b2, h, N);
    gather_kernel<<<(N + 3) / 4, 256, 0, stream>>>(rowptr, edata, h, out, N);
}